// Round 6
// baseline (148.457 us; speedup 1.0000x reference)
//
#include <hip/hip_runtime.h>
#include <cstdint>

#define N_SEQ 8
#define B_DIM 64
#define H_DIM 128
#define F_DIM 256
#define HS 64

typedef __attribute__((ext_vector_type(8))) short short8;
typedef __attribute__((ext_vector_type(4))) float floatx4;

__device__ __forceinline__ ushort f2bf(float f) {
    union { float f; uint32_t u; } v; v.f = f;
    uint32_t r = v.u + 0x7FFF + ((v.u >> 16) & 1);   // RNE
    return (ushort)(r >> 16);
}

// async 16B-per-lane global -> LDS (wave-uniform LDS base + lane*16)
__device__ __forceinline__ void async_ld16(const ushort* g, ushort* lds) {
    __builtin_amdgcn_global_load_lds(
        (const __attribute__((address_space(1))) unsigned int*)g,
        (__attribute__((address_space(3))) unsigned int*)lds,
        16, 0, 0);
}

// ---------------- W transpose + cast: Wtb[n=192][k=256] bf16 ----------------
__global__ __launch_bounds__(256) void prep_w(
    const float* __restrict__ Wq, const float* __restrict__ Wk,
    const float* __restrict__ Wv, ushort* __restrict__ Wtb)
{
    const int n = blockIdx.x;                 // 0..191
    const float* W = (n < 64) ? Wq : (n < 128) ? Wk : Wv;
    const int c = n & 63;
    const int k = threadIdx.x;                // 0..255
    Wtb[n * 256 + k] = f2bf(W[k * 64 + c]);
}

// ---------------- QKV projection via MFMA (round-3 form, unchanged) --------
#define XS_STRIDE 264   // 256 + 8 pad (bf16 elems)
__global__ __launch_bounds__(256, 4) void proj_mfma(
    const float* __restrict__ x, const ushort* __restrict__ Wtb,
    ushort* __restrict__ Qb, ushort* __restrict__ Kb, ushort* __restrict__ Vtb)
{
    __shared__ ushort xs[64 * XS_STRIDE];     // 33,792 B
    const int t = threadIdx.x;
    const int blk = blockIdx.x;
    const int64_t row0 = (int64_t)blk * 64;

    const float4* xg = (const float4*)(x + row0 * F_DIM);
    #pragma unroll
    for (int u = 0; u < 8; ++u) {
        const int idx = t + 256 * u;
        const int row = idx >> 5;
        const int c8 = (idx & 31) * 8;
        const float4 a = xg[idx * 2];
        const float4 b = xg[idx * 2 + 1];
        *(ushort4*)&xs[row * XS_STRIDE + c8] =
            make_ushort4(f2bf(a.x), f2bf(a.y), f2bf(a.z), f2bf(a.w));
        *(ushort4*)&xs[row * XS_STRIDE + c8 + 4] =
            make_ushort4(f2bf(b.x), f2bf(b.y), f2bf(b.z), f2bf(b.w));
    }
    __syncthreads();

    const int w = t >> 6, lane = t & 63;
    const int q16 = lane >> 4, l16 = lane & 15;
    const int n0 = w * 48;

    floatx4 acc[4][3];
    #pragma unroll
    for (int mt = 0; mt < 4; ++mt)
        #pragma unroll
        for (int nt = 0; nt < 3; ++nt) acc[mt][nt] = (floatx4){0.f, 0.f, 0.f, 0.f};

    short8 nb[3];
    #pragma unroll
    for (int nt = 0; nt < 3; ++nt)
        nb[nt] = *(const short8*)&Wtb[(n0 + nt * 16 + l16) * 256 + q16 * 8];

    for (int ks = 0; ks < 8; ++ks) {
        short8 cur[3];
        #pragma unroll
        for (int nt = 0; nt < 3; ++nt) cur[nt] = nb[nt];
        if (ks < 7) {
            #pragma unroll
            for (int nt = 0; nt < 3; ++nt)
                nb[nt] = *(const short8*)&Wtb[(n0 + nt * 16 + l16) * 256 + (ks + 1) * 32 + q16 * 8];
        }
        #pragma unroll
        for (int mt = 0; mt < 4; ++mt) {
            const short8 afr = *(const short8*)&xs[(mt * 16 + l16) * XS_STRIDE + ks * 32 + q16 * 8];
            #pragma unroll
            for (int nt = 0; nt < 3; ++nt)
                acc[mt][nt] = __builtin_amdgcn_mfma_f32_16x16x32_bf16(afr, cur[nt], acc[mt][nt], 0, 0, 0);
        }
    }

    const float qscale = 0.0625f * 1.44269504f;
    #pragma unroll
    for (int mt = 0; mt < 4; ++mt) {
        const int64_t g = row0 + mt * 16 + q16 * 4;
        #pragma unroll
        for (int nt = 0; nt < 3; ++nt) {
            const int ntb = n0 + nt * 16;             // wave-uniform
            const int n = ntb + l16;
            if (ntb < 64) {
                #pragma unroll
                for (int r = 0; r < 4; ++r)
                    Qb[(g + r) * 64 + n] = f2bf(acc[mt][nt][r] * qscale);
            } else if (ntb < 128) {
                #pragma unroll
                for (int r = 0; r < 4; ++r)
                    Kb[(g + r) * 64 + (n - 64)] = f2bf(acc[mt][nt][r]);
            } else {
                const int d = n - 128;
                const int ib = (int)(g >> 7);
                const int h = (int)(g & 127);
                *(ushort4*)&Vtb[((int64_t)(ib * 64 + d)) * 128 + h] =
                    make_ushort4(f2bf(acc[mt][nt][0]), f2bf(acc[mt][nt][1]),
                                 f2bf(acc[mt][nt][2]), f2bf(acc[mt][nt][3]));
            }
        }
    }
}

// ---------------- attention: k-split wave pairs ----------------------------
// 512 blocks (j,b), 512 threads, 8 waves: wave = (pg, kg), pg=w>>1 owns 32
// p-rows (2 pt tiles), kg=w&1 owns one 64-k half of every tile. Each wave
// reads ONLY its k-half of K/V from LDS -> per-wave shared-operand LDS
// volume halves vs round 5. Full K/V tiles staged per i (async
// global_load_lds, frag-linear, double-buffered). Deferred normalization
// makes the k-split cheap: only lsum crosses the wave pair (Ls buffer +
// exchange barrier per i); of-partials combined once at kernel end through
// reused Ks space. LDS = 32K(Ks)+32K(Vt)+10K(Ps)+4K(Ls) = 78 KB -> 2
// blocks/CU = 16 waves/CU = 4 waves/SIMD (same TLP as round 5).
#define PT_STRIDE 40    // 32 + 8 pad (80 B rows, 16B-aligned b128 reads)
__global__ __launch_bounds__(512, 4) void attn_mfma(
    const ushort* __restrict__ Qb, const ushort* __restrict__ Kb,
    const ushort* __restrict__ Vtb, float* __restrict__ out)
{
    __shared__ __align__(16) ushort Ks[2][2][4096];  // [kg][buf][8 frags x 1KB]
    __shared__ __align__(16) ushort Vt[2][2][4096];  // [kg][buf][8 frags x 1KB]
    __shared__ __align__(16) ushort Ps[8][16 * PT_STRIDE];  // 10,240 B
    __shared__ float Ls[2][4][2][64];                // [kg][pg][pt][q16*16+l16]

    const int t = threadIdx.x;
    const int blk = blockIdx.x;
    const int b  = ((blk & 7) << 3) | ((blk >> 3) & 7);   // XCD-major b
    const int j  = blk >> 6;
    const int jb = j * 64 + b;

    const int w = t >> 6, lane = t & 63;      // w = 0..7
    const int pg = w >> 1, kg = w & 1;
    const int q16 = lane >> 4, l16 = lane & 15;

    // staging: wave (pg,kg) stages stream kg's frags {2pg, 2pg+1} of K and V.
    // K frag fi: k-row kg*64+(fi&3)*16+l16, d-col (fi>>2)*32+q16*8
    // V frag fi: d-row (fi&3)*16+l16, k-col kg*64+(fi>>2)*32+q16*8
    int koff[2], voff[2], lk[2];
    #pragma unroll
    for (int u = 0; u < 2; ++u) {
        const int fi = pg * 2 + u;
        koff[u] = (kg * 64 + (fi & 3) * 16 + l16) * 64 + (fi >> 2) * 32 + q16 * 8;
        voff[u] = ((fi & 3) * 16 + l16) * 128 + kg * 64 + (fi >> 2) * 32 + q16 * 8;
        lk[u] = __builtin_amdgcn_readfirstlane(fi * 512);   // frag-linear dest
    }

    // Q B-frags for this wave's 2 p-tiles (Qb pre-scaled by log2e/16)
    const int prow = jb * H_DIM + pg * 32 + l16;
    short8 qa[2][2];
    #pragma unroll
    for (int pt = 0; pt < 2; ++pt)
        #pragma unroll
        for (int ks = 0; ks < 2; ++ks)
            qa[pt][ks] = *(const short8*)&Qb[(prow + pt * 16) * 64 + ks * 32 + q16 * 8];

    floatx4 of[4][2];
    #pragma unroll
    for (int mt = 0; mt < 4; ++mt)
        #pragma unroll
        for (int pt = 0; pt < 2; ++pt) of[mt][pt] = (floatx4){0.f, 0.f, 0.f, 0.f};

    // ---- prologue: stage tile 0 (this wave's k-half) into buffer 0 ----
    {
        const ushort* kgp = Kb + ((0 * B_DIM + b) << 13);
        const ushort* vgp = Vtb + ((0 * B_DIM + b) << 13);
        #pragma unroll
        for (int u = 0; u < 2; ++u) {
            async_ld16(kgp + koff[u], &Ks[kg][0][lk[u]]);
            async_ld16(vgp + voff[u], &Vt[kg][0][lk[u]]);
        }
    }

    for (int i = 0; i < N_SEQ; ++i) {
        const int buf = i & 1;
        __syncthreads();   // drains stage(i); protects buf's prior readers

        if (i < N_SEQ - 1) {   // stage k-half of tile i+1 during compute
            const ushort* kgp = Kb + (((i + 1) * B_DIM + b) << 13);
            const ushort* vgp = Vtb + (((i + 1) * B_DIM + b) << 13);
            #pragma unroll
            for (int u = 0; u < 2; ++u) {
                async_ld16(kgp + koff[u], &Ks[kg][buf ^ 1][lk[u]]);
                async_ld16(vgp + voff[u], &Vt[kg][buf ^ 1][lk[u]]);
            }
        }

        float lsum[2];
        floatx4 tmp[4][2];
        #pragma unroll
        for (int mt = 0; mt < 4; ++mt)
            #pragma unroll
            for (int pt = 0; pt < 2; ++pt) tmp[mt][pt] = (floatx4){0.f, 0.f, 0.f, 0.f};

        #pragma unroll
        for (int pt = 0; pt < 2; ++pt) {
            // ---- S^T = K Q^T on this wave's 64-k half, 16-p tile pt ----
            floatx4 sf[4];
            #pragma unroll
            for (int kt = 0; kt < 4; ++kt) sf[kt] = (floatx4){0.f, 0.f, 0.f, 0.f};
            #pragma unroll
            for (int ks = 0; ks < 2; ++ks)
                #pragma unroll
                for (int kt = 0; kt < 4; ++kt) {
                    const short8 ak = *(const short8*)&Ks[kg][buf][(ks * 4 + kt) * 512 + lane * 8];
                    sf[kt] = __builtin_amdgcn_mfma_f32_16x16x32_bf16(ak, qa[pt][ks], sf[kt], 0, 0, 0);
                }

            // ---- exp2 + partial row-sum over this k-half ----
            float l = 0.f;
            #pragma unroll
            for (int kt = 0; kt < 4; ++kt)
                #pragma unroll
                for (int r = 0; r < 4; ++r) {
                    sf[kt][r] = __builtin_amdgcn_exp2f(sf[kt][r]);
                    l += sf[kt][r];
                }
            l += __shfl_xor(l, 16);
            l += __shfl_xor(l, 32);
            lsum[pt] = l;

            // ---- PV partial (UNNORMALIZED P), kq-chunked ----
            #pragma unroll
            for (int kq = 0; kq < 2; ++kq) {
                #pragma unroll
                for (int tt = 0; tt < 2; ++tt) {
                    const int kt = kq * 2 + tt;
                    *(ushort4*)&Ps[w][l16 * PT_STRIDE + tt * 16 + q16 * 4] =
                        make_ushort4(f2bf(sf[kt][0]), f2bf(sf[kt][1]),
                                     f2bf(sf[kt][2]), f2bf(sf[kt][3]));
                }
                const short8 bp = *(const short8*)&Ps[w][l16 * PT_STRIDE + q16 * 8];
                #pragma unroll
                for (int mt = 0; mt < 4; ++mt) {
                    const short8 av = *(const short8*)&Vt[kg][buf][(kq * 4 + mt) * 512 + lane * 8];
                    tmp[mt][pt] = __builtin_amdgcn_mfma_f32_16x16x32_bf16(av, bp, tmp[mt][pt], 0, 0, 0);
                }
            }

            Ls[kg][pg][pt][q16 * 16 + l16] = lsum[pt];
        }

        __syncthreads();   // lsum exchange (also separates Ls reuse across i)

        #pragma unroll
        for (int pt = 0; pt < 2; ++pt) {
            const float inv = __builtin_amdgcn_rcpf(
                lsum[pt] + Ls[kg ^ 1][pg][pt][q16 * 16 + l16]);
            #pragma unroll
            for (int mt = 0; mt < 4; ++mt)
                #pragma unroll
                for (int r = 0; r < 4; ++r)
                    of[mt][pt][r] += tmp[mt][pt][r] * inv;
        }
    }

    // ---- combine k-partners through reused Ks space (32 KB), then store ----
    __syncthreads();   // all done with Ks
    float* Ob = (float*)&Ks[0][0][0];
    if (kg == 1) {
        #pragma unroll
        for (int mt = 0; mt < 4; ++mt)
            #pragma unroll
            for (int pt = 0; pt < 2; ++pt)
                *(floatx4*)&Ob[(pg * 8 + mt * 2 + pt) * 256 + lane * 4] = of[mt][pt];
    }
    __syncthreads();
    if (kg == 0) {
        #pragma unroll
        for (int mt = 0; mt < 4; ++mt)
            #pragma unroll
            for (int pt = 0; pt < 2; ++pt) {
                const floatx4 o2 = *(const floatx4*)&Ob[(pg * 8 + mt * 2 + pt) * 256 + lane * 4];
                #pragma unroll
                for (int r = 0; r < 4; ++r) of[mt][pt][r] += o2[r];
            }
        #pragma unroll
        for (int pt = 0; pt < 2; ++pt)
            #pragma unroll
            for (int mt = 0; mt < 4; ++mt)
                *(float4*)&out[(int64_t)(prow + pt * 16) * HS + mt * 16 + q16 * 4] =
                    make_float4(of[mt][pt][0], of[mt][pt][1], of[mt][pt][2], of[mt][pt][3]);
    }
}

extern "C" void kernel_launch(void* const* d_in, const int* in_sizes, int n_in,
                              void* d_out, int out_size, void* d_ws, size_t ws_size,
                              hipStream_t stream)
{
    const float* x  = (const float*)d_in[0];
    const float* Wq = (const float*)d_in[1];
    const float* Wk = (const float*)d_in[2];
    const float* Wv = (const float*)d_in[3];
    float* out = (float*)d_out;

    const size_t qkv = (size_t)N_SEQ * B_DIM * H_DIM * HS;   // 4,194,304 elems
    ushort* Qb  = (ushort*)d_ws;
    ushort* Kb  = Qb + qkv;
    ushort* Vtb = Kb + qkv;
    ushort* Wtb = Vtb + qkv;                                 // 192*256 elems

    prep_w<<<192, 256, 0, stream>>>(Wq, Wk, Wv, Wtb);
    proj_mfma<<<(N_SEQ * B_DIM * H_DIM) / 64, 256, 0, stream>>>(x, Wtb, Qb, Kb, Vtb);
    attn_mfma<<<N_SEQ * B_DIM, 512, 0, stream>>>(Qb, Kb, Vtb, out);
}

// Round 7
// 143.458 us; speedup vs baseline: 1.0348x; 1.0348x over previous
//
#include <hip/hip_runtime.h>
#include <cstdint>

#define N_SEQ 8
#define B_DIM 64
#define H_DIM 128
#define F_DIM 256
#define HS 64

typedef __attribute__((ext_vector_type(8))) short short8;
typedef __attribute__((ext_vector_type(4))) float floatx4;

__device__ __forceinline__ ushort f2bf(float f) {
    union { float f; uint32_t u; } v; v.f = f;
    uint32_t r = v.u + 0x7FFF + ((v.u >> 16) & 1);   // RNE
    return (ushort)(r >> 16);
}

// async 16B-per-lane global -> LDS (wave-uniform LDS base + lane*16)
__device__ __forceinline__ void async_ld16(const ushort* g, ushort* lds) {
    __builtin_amdgcn_global_load_lds(
        (const __attribute__((address_space(1))) unsigned int*)g,
        (__attribute__((address_space(3))) unsigned int*)lds,
        16, 0, 0);
}

// ---------------- W transpose + cast: Wtb[n=192][k=256] bf16 ----------------
__global__ __launch_bounds__(256) void prep_w(
    const float* __restrict__ Wq, const float* __restrict__ Wk,
    const float* __restrict__ Wv, ushort* __restrict__ Wtb)
{
    const int n = blockIdx.x;                 // 0..191
    const float* W = (n < 64) ? Wq : (n < 128) ? Wk : Wv;
    const int c = n & 63;
    const int k = threadIdx.x;                // 0..255
    Wtb[n * 256 + k] = f2bf(W[k * 64 + c]);
}

// ---------------- QKV projection via MFMA (round-3 form, unchanged) --------
#define XS_STRIDE 264   // 256 + 8 pad (bf16 elems)
__global__ __launch_bounds__(256, 4) void proj_mfma(
    const float* __restrict__ x, const ushort* __restrict__ Wtb,
    ushort* __restrict__ Qb, ushort* __restrict__ Kb, ushort* __restrict__ Vtb)
{
    __shared__ ushort xs[64 * XS_STRIDE];     // 33,792 B
    const int t = threadIdx.x;
    const int blk = blockIdx.x;
    const int64_t row0 = (int64_t)blk * 64;

    const float4* xg = (const float4*)(x + row0 * F_DIM);
    #pragma unroll
    for (int u = 0; u < 8; ++u) {
        const int idx = t + 256 * u;
        const int row = idx >> 5;
        const int c8 = (idx & 31) * 8;
        const float4 a = xg[idx * 2];
        const float4 b = xg[idx * 2 + 1];
        *(ushort4*)&xs[row * XS_STRIDE + c8] =
            make_ushort4(f2bf(a.x), f2bf(a.y), f2bf(a.z), f2bf(a.w));
        *(ushort4*)&xs[row * XS_STRIDE + c8 + 4] =
            make_ushort4(f2bf(b.x), f2bf(b.y), f2bf(b.z), f2bf(b.w));
    }
    __syncthreads();

    const int w = t >> 6, lane = t & 63;
    const int q16 = lane >> 4, l16 = lane & 15;
    const int n0 = w * 48;

    floatx4 acc[4][3];
    #pragma unroll
    for (int mt = 0; mt < 4; ++mt)
        #pragma unroll
        for (int nt = 0; nt < 3; ++nt) acc[mt][nt] = (floatx4){0.f, 0.f, 0.f, 0.f};

    short8 nb[3];
    #pragma unroll
    for (int nt = 0; nt < 3; ++nt)
        nb[nt] = *(const short8*)&Wtb[(n0 + nt * 16 + l16) * 256 + q16 * 8];

    for (int ks = 0; ks < 8; ++ks) {
        short8 cur[3];
        #pragma unroll
        for (int nt = 0; nt < 3; ++nt) cur[nt] = nb[nt];
        if (ks < 7) {
            #pragma unroll
            for (int nt = 0; nt < 3; ++nt)
                nb[nt] = *(const short8*)&Wtb[(n0 + nt * 16 + l16) * 256 + (ks + 1) * 32 + q16 * 8];
        }
        #pragma unroll
        for (int mt = 0; mt < 4; ++mt) {
            const short8 afr = *(const short8*)&xs[(mt * 16 + l16) * XS_STRIDE + ks * 32 + q16 * 8];
            #pragma unroll
            for (int nt = 0; nt < 3; ++nt)
                acc[mt][nt] = __builtin_amdgcn_mfma_f32_16x16x32_bf16(afr, cur[nt], acc[mt][nt], 0, 0, 0);
        }
    }

    const float qscale = 0.0625f * 1.44269504f;
    #pragma unroll
    for (int mt = 0; mt < 4; ++mt) {
        const int64_t g = row0 + mt * 16 + q16 * 4;
        #pragma unroll
        for (int nt = 0; nt < 3; ++nt) {
            const int ntb = n0 + nt * 16;             // wave-uniform
            const int n = ntb + l16;
            if (ntb < 64) {
                #pragma unroll
                for (int r = 0; r < 4; ++r)
                    Qb[(g + r) * 64 + n] = f2bf(acc[mt][nt][r] * qscale);
            } else if (ntb < 128) {
                #pragma unroll
                for (int r = 0; r < 4; ++r)
                    Kb[(g + r) * 64 + (n - 64)] = f2bf(acc[mt][nt][r]);
            } else {
                const int d = n - 128;
                const int ib = (int)(g >> 7);
                const int h = (int)(g & 127);
                *(ushort4*)&Vtb[((int64_t)(ib * 64 + d)) * 128 + h] =
                    make_ushort4(f2bf(acc[mt][nt][0]), f2bf(acc[mt][nt][1]),
                                 f2bf(acc[mt][nt][2]), f2bf(acc[mt][nt][3]));
            }
        }
    }
}

// ---------------- attention: full tiles, 8 waves, 8 barriers ---------------
// 512 blocks (j,b), 512 threads, 8 waves; each wave owns ONE p-16-group
// (w*16+l16) and processes the FULL 128-k tile per i (round-3 fragment
// geometry; staging reindexed fi = w*2+u). 8 barriers total (half of round
// 5): kernel is barrier/lockstep-bound (round-6 evidence), so fewer, fatter
// substeps. Same TLP as round 5: LDS = 32K(Ks)+32K(Vt)+10K(Ps) = 75,776 B
// -> 2 blocks/CU = 16 waves/CU = 4 waves/SIMD.
// Deferred normalization: P packed UNNORMALIZED; of += tmp*inv per i.
#define PT_STRIDE 40    // 32 + 8 pad (80 B rows, 16B-aligned b128 reads)
__global__ __launch_bounds__(512, 4) void attn_mfma(
    const ushort* __restrict__ Qb, const ushort* __restrict__ Kb,
    const ushort* __restrict__ Vtb, float* __restrict__ out)
{
    __shared__ __align__(16) ushort Ks[2][8192];   // 2 x 16 KB, 16 frags x 1 KB
    __shared__ __align__(16) ushort Vt[2][8192];   // 2 x 16 KB, 16 frags x 1 KB
    __shared__ __align__(16) ushort Ps[8][16 * PT_STRIDE];  // 10,240 B

    const int t = threadIdx.x;
    const int blk = blockIdx.x;
    const int b  = ((blk & 7) << 3) | ((blk >> 3) & 7);   // XCD-major b
    const int j  = blk >> 6;
    const int jb = j * 64 + b;

    const int w = t >> 6, lane = t & 63;      // w = 0..7
    const int q16 = lane >> 4, l16 = lane & 15;

    // staging: wave w stages K frags {2w,2w+1} and V frags {2w,2w+1}.
    // K frag fi: ks=fi>>3, nt=fi&7 ; elem = (nt*16+l16)*64 + ks*32 + q16*8
    // V frag fi: kq=fi>>2, mt=fi&3 ; elem = (mt*16+l16)*128 + kq*32 + q16*8
    int koff[2], voff[2], lk[2];
    #pragma unroll
    for (int u = 0; u < 2; ++u) {
        const int fi = w * 2 + u;
        koff[u] = ((fi & 7) * 16 + l16) * 64 + (fi >> 3) * 32 + q16 * 8;
        voff[u] = ((fi & 3) * 16 + l16) * 128 + (fi >> 2) * 32 + q16 * 8;
        lk[u] = __builtin_amdgcn_readfirstlane(fi * 512);   // frag-linear dest
    }

    // Q B-frags for this wave's p-group (Qb pre-scaled by log2e/16)
    const int prow = jb * H_DIM + w * 16 + l16;
    short8 qa[2];
    #pragma unroll
    for (int ks = 0; ks < 2; ++ks)
        qa[ks] = *(const short8*)&Qb[prow * 64 + ks * 32 + q16 * 8];

    floatx4 of[4];
    #pragma unroll
    for (int mt = 0; mt < 4; ++mt) of[mt] = (floatx4){0.f, 0.f, 0.f, 0.f};

    // ---- prologue: stage tile 0 into buffer 0 ----
    {
        const ushort* kg = Kb + ((0 * B_DIM + b) << 13);
        const ushort* vg = Vtb + ((0 * B_DIM + b) << 13);
        #pragma unroll
        for (int u = 0; u < 2; ++u) {
            async_ld16(kg + koff[u], &Ks[0][lk[u]]);
            async_ld16(vg + voff[u], &Vt[0][lk[u]]);
        }
    }

    for (int i = 0; i < N_SEQ; ++i) {
        const int buf = i & 1;
        __syncthreads();   // drains stage(i); protects buf's prior readers

        if (i < N_SEQ - 1) {   // stage tile i+1 during compute
            const ushort* kg = Kb + (((i + 1) * B_DIM + b) << 13);
            const ushort* vg = Vtb + (((i + 1) * B_DIM + b) << 13);
            #pragma unroll
            for (int u = 0; u < 2; ++u) {
                async_ld16(kg + koff[u], &Ks[buf ^ 1][lk[u]]);
                async_ld16(vg + voff[u], &Vt[buf ^ 1][lk[u]]);
            }
        }

        // ---- S^T = K Q^T over full 128-k tile (8 nt groups) ----
        floatx4 sf[8];
        #pragma unroll
        for (int nt = 0; nt < 8; ++nt) sf[nt] = (floatx4){0.f, 0.f, 0.f, 0.f};
        #pragma unroll
        for (int ks = 0; ks < 2; ++ks)
            #pragma unroll
            for (int nt = 0; nt < 8; ++nt) {
                const short8 ak = *(const short8*)&Ks[buf][(ks * 8 + nt) * 512 + lane * 8];
                sf[nt] = __builtin_amdgcn_mfma_f32_16x16x32_bf16(ak, qa[ks], sf[nt], 0, 0, 0);
            }

        // ---- exp2 + row-sum; inv consumed only at i-end ----
        float l = 0.f;
        #pragma unroll
        for (int nt = 0; nt < 8; ++nt)
            #pragma unroll
            for (int r = 0; r < 4; ++r) {
                sf[nt][r] = __builtin_amdgcn_exp2f(sf[nt][r]);
                l += sf[nt][r];
            }
        l += __shfl_xor(l, 16);
        l += __shfl_xor(l, 32);
        const float inv = __builtin_amdgcn_rcpf(l);

        // ---- O^T += V^T P^T, kq-chunked; P packed UNNORMALIZED ----
        floatx4 tmp[4];
        #pragma unroll
        for (int mt = 0; mt < 4; ++mt) tmp[mt] = (floatx4){0.f, 0.f, 0.f, 0.f};

        #pragma unroll
        for (int kq = 0; kq < 4; ++kq) {
            #pragma unroll
            for (int tt = 0; tt < 2; ++tt) {
                const int nt = kq * 2 + tt;
                *(ushort4*)&Ps[w][l16 * PT_STRIDE + tt * 16 + q16 * 4] =
                    make_ushort4(f2bf(sf[nt][0]), f2bf(sf[nt][1]),
                                 f2bf(sf[nt][2]), f2bf(sf[nt][3]));
            }
            const short8 bp = *(const short8*)&Ps[w][l16 * PT_STRIDE + q16 * 8];
            #pragma unroll
            for (int mt = 0; mt < 4; ++mt) {
                const short8 av = *(const short8*)&Vt[buf][(kq * 4 + mt) * 512 + lane * 8];
                tmp[mt] = __builtin_amdgcn_mfma_f32_16x16x32_bf16(av, bp, tmp[mt], 0, 0, 0);
            }
        }

        #pragma unroll
        for (int mt = 0; mt < 4; ++mt)
            #pragma unroll
            for (int r = 0; r < 4; ++r)
                of[mt][r] += tmp[mt][r] * inv;
    }

    // ---- epilogue: O^T C-layout -> float4 stores (4 consecutive d) ----
    #pragma unroll
    for (int mt = 0; mt < 4; ++mt)
        *(float4*)&out[(int64_t)prow * HS + mt * 16 + q16 * 4] =
            make_float4(of[mt][0], of[mt][1], of[mt][2], of[mt][3]);
}

extern "C" void kernel_launch(void* const* d_in, const int* in_sizes, int n_in,
                              void* d_out, int out_size, void* d_ws, size_t ws_size,
                              hipStream_t stream)
{
    const float* x  = (const float*)d_in[0];
    const float* Wq = (const float*)d_in[1];
    const float* Wk = (const float*)d_in[2];
    const float* Wv = (const float*)d_in[3];
    float* out = (float*)d_out;

    const size_t qkv = (size_t)N_SEQ * B_DIM * H_DIM * HS;   // 4,194,304 elems
    ushort* Qb  = (ushort*)d_ws;
    ushort* Kb  = Qb + qkv;
    ushort* Vtb = Kb + qkv;
    ushort* Wtb = Vtb + qkv;                                 // 192*256 elems

    prep_w<<<192, 256, 0, stream>>>(Wq, Wk, Wv, Wtb);
    proj_mfma<<<(N_SEQ * B_DIM * H_DIM) / 64, 256, 0, stream>>>(x, Wtb, Qb, Kb, Vtb);
    attn_mfma<<<N_SEQ * B_DIM, 512, 0, stream>>>(Qb, Kb, Vtb, out);
}